// Round 1
// baseline (380.292 us; speedup 1.0000x reference)
//
#include <hip/hip_runtime.h>
#include <math.h>

#define EPSF 1e-5f

// =====================================================================
// Kernel 1: fused projection GEMM
//   proj[512][2048] = [ relu(x@Wk+bk) (512 cols) | x@Wv+bv (1024) | relu(x@Wq+bq) (512) ]
//   64x64 tile, BK=16, 256 threads, 4x4 micro-tile.
// =====================================================================
__global__ __launch_bounds__(256) void proj_gemm_kernel(
    const float* __restrict__ x,
    const float* __restrict__ Wk, const float* __restrict__ bk,
    const float* __restrict__ Wv, const float* __restrict__ bv,
    const float* __restrict__ Wq, const float* __restrict__ bq,
    float* __restrict__ proj)
{
  __shared__ float As[16][68];   // [k][m]
  __shared__ float Bs[16][68];   // [k][n]
  const int col0 = blockIdx.x * 64;
  const int row0 = blockIdx.y * 64;
  const float* Bp; const float* bias; int ldb, bcol, relu;
  if (col0 < 512)       { Bp = Wk; bias = bk; ldb = 512;  bcol = col0;        relu = 1; }
  else if (col0 < 1536) { Bp = Wv; bias = bv; ldb = 1024; bcol = col0 - 512;  relu = 0; }
  else                  { Bp = Wq; bias = bq; ldb = 512;  bcol = col0 - 1536; relu = 1; }
  const int tid = threadIdx.x;
  const int tr = tid >> 4, tc = tid & 15;
  float acc[4][4] = {};
  for (int k0 = 0; k0 < 1024; k0 += 16) {
    {
      int r = tid >> 2, kk = (tid & 3) << 2;
      float4 a4 = *(const float4*)&x[(size_t)(row0 + r) * 1024 + k0 + kk];
      As[kk+0][r] = a4.x; As[kk+1][r] = a4.y; As[kk+2][r] = a4.z; As[kk+3][r] = a4.w;
    }
    {
      int kr = tid >> 4, cc = (tid & 15) << 2;
      *(float4*)&Bs[kr][cc] = *(const float4*)&Bp[(size_t)(k0 + kr) * ldb + bcol + cc];
    }
    __syncthreads();
    #pragma unroll
    for (int k = 0; k < 16; ++k) {
      float4 av4 = *(const float4*)&As[k][tr*4];
      float4 bv4 = *(const float4*)&Bs[k][tc*4];
      float av[4] = {av4.x, av4.y, av4.z, av4.w};
      float bb[4] = {bv4.x, bv4.y, bv4.z, bv4.w};
      #pragma unroll
      for (int i = 0; i < 4; ++i)
        #pragma unroll
        for (int j = 0; j < 4; ++j)
          acc[i][j] = fmaf(av[i], bb[j], acc[i][j]);
    }
    __syncthreads();
  }
  #pragma unroll
  for (int i = 0; i < 4; ++i) {
    int r = row0 + tr*4 + i;
    #pragma unroll
    for (int j = 0; j < 4; ++j) {
      int cl = tc*4 + j;
      float v = acc[i][j] + bias[bcol + cl];
      if (relu) v = fmaxf(v, 0.f);
      proj[(size_t)r * 2048 + col0 + cl] = v;
    }
  }
}

// =====================================================================
// Kernel 2: fused memory kernel. One workgroup per batch (512 wgs).
//   Each of 4 waves independently handles 512 m-rows in tiles of 8.
//   Per tile: S = qa@fk^T (factorized num), den=sum_h S, num=S@v,
//   update/write_prob/new_mem/fkm elementwise, then 8x8 register-tiled
//   outer-product accumulation of matrix2 (64 acc regs/lane).
//   Epilogue: in-wg reduce matrix2/norm2, compute attn -> ws.
// =====================================================================
__global__ __launch_bounds__(256, 2) void fused_mem_kernel(
    const float* __restrict__ memories,   // [512][2048][64]
    const float* __restrict__ addresses,  // [2048][64]
    const float* __restrict__ proj,       // [512][2048] = fk|v|fq
    float* __restrict__ attn)             // [512][512]
{
  __shared__ float pbuf[2048];            // fk[8][64] | v[8][128] | fq[8][64]
  __shared__ float nm_lds[4][8][76];
  __shared__ float fkm_lds[4][8][76];
  __shared__ float n2stage[4][64];
  __shared__ float norm2_lds[64];
  __shared__ float den2_lds[8];
  __shared__ float stage[4][16][64];

  const int b    = blockIdx.x;
  const int tid  = threadIdx.x;
  const int wave = tid >> 6;
  const int lane = tid & 63;
  const int ml   = lane >> 3;   // 0..7 : m-row within tile; also d-block in phase D
  const int l8   = lane & 7;    // 0..7 : d/e slice;        also e-block in phase D

  // stage fk|v|fq (2048 floats) into LDS
  {
    const float* prow = proj + (size_t)b * 2048;
    float4 p0 = *(const float4*)&prow[tid * 8];
    float4 p1 = *(const float4*)&prow[tid * 8 + 4];
    *(float4*)&pbuf[tid * 8]     = p0;
    *(float4*)&pbuf[tid * 8 + 4] = p1;
  }
  const float* fkb = pbuf;
  const float* vb  = pbuf + 512;
  const float* fqb = pbuf + 1536;

  float acc[64];
  #pragma unroll
  for (int i = 0; i < 64; ++i) acc[i] = 0.f;
  float n2acc[8];
  #pragma unroll
  for (int j = 0; j < 8; ++j) n2acc[j] = 0.f;

  __syncthreads();

  const int mbase = wave * 512;
  #pragma unroll 1
  for (int t = 0; t < 64; ++t) {
    const int m = mbase + t * 8 + ml;

    // ---- loads: addresses slice (also reused as raw addr for mem_key), memories slice
    const float* arow = addresses + (size_t)m * 64 + l8 * 8;
    float4 a0 = *(const float4*)arow;
    float4 a1 = *(const float4*)(arow + 4);
    float ar[8] = {a0.x,a0.y,a0.z,a0.w,a1.x,a1.y,a1.z,a1.w};
    const float* mrow = memories + ((size_t)b * 2048 + m) * 64 + l8 * 8;
    float4 m0 = *(const float4*)mrow;
    float4 m1 = *(const float4*)(mrow + 4);
    float mem[8] = {m0.x,m0.y,m0.z,m0.w,m1.x,m1.y,m1.z,m1.w};
    float qa[8];
    #pragma unroll
    for (int j = 0; j < 8; ++j) qa[j] = fmaxf(ar[j], 0.f);

    // ---- phase B: partial S[h] over this lane's 8-d slice, then 8-lane-group reduce
    float S[8];
    #pragma unroll
    for (int h = 0; h < 8; ++h) {
      const float* fr = fkb + h * 64 + l8 * 8;
      float4 f0 = *(const float4*)fr;
      float4 f1 = *(const float4*)(fr + 4);
      float s;
      s = qa[0] * f0.x;
      s = fmaf(qa[1], f0.y, s);
      s = fmaf(qa[2], f0.z, s);
      s = fmaf(qa[3], f0.w, s);
      s = fmaf(qa[4], f1.x, s);
      s = fmaf(qa[5], f1.y, s);
      s = fmaf(qa[6], f1.z, s);
      s = fmaf(qa[7], f1.w, s);
      S[h] = s;
    }
    #pragma unroll
    for (int h = 0; h < 8; ++h) {
      float s = S[h];
      s += __shfl_xor(s, 1);
      s += __shfl_xor(s, 2);
      s += __shfl_xor(s, 4);
      S[h] = s;
    }
    float den = ((S[0]+S[1])+(S[2]+S[3])) + ((S[4]+S[5])+(S[6]+S[7])) + EPSF;
    float rden = 1.f / den;

    // ---- phase C: num (e and write halves), elementwise, new_mem/fkm
    float nume[8], numw[8];
    #pragma unroll
    for (int j = 0; j < 8; ++j) { nume[j] = 0.f; numw[j] = 0.f; }
    #pragma unroll
    for (int h = 0; h < 8; ++h) {
      const float* vr = vb + h * 128 + l8 * 8;
      float4 e0 = *(const float4*)vr;
      float4 e1 = *(const float4*)(vr + 4);
      float4 w0 = *(const float4*)(vr + 64);
      float4 w1 = *(const float4*)(vr + 68);
      float sh = S[h];
      nume[0] = fmaf(sh, e0.x, nume[0]);
      nume[1] = fmaf(sh, e0.y, nume[1]);
      nume[2] = fmaf(sh, e0.z, nume[2]);
      nume[3] = fmaf(sh, e0.w, nume[3]);
      nume[4] = fmaf(sh, e1.x, nume[4]);
      nume[5] = fmaf(sh, e1.y, nume[5]);
      nume[6] = fmaf(sh, e1.z, nume[6]);
      nume[7] = fmaf(sh, e1.w, nume[7]);
      numw[0] = fmaf(sh, w0.x, numw[0]);
      numw[1] = fmaf(sh, w0.y, numw[1]);
      numw[2] = fmaf(sh, w0.z, numw[2]);
      numw[3] = fmaf(sh, w0.w, numw[3]);
      numw[4] = fmaf(sh, w1.x, numw[4]);
      numw[5] = fmaf(sh, w1.y, numw[5]);
      numw[6] = fmaf(sh, w1.z, numw[6]);
      numw[7] = fmaf(sh, w1.w, numw[7]);
    }
    float nmv[8], fkv[8];
    #pragma unroll
    for (int j = 0; j < 8; ++j) {
      float upd = nume[j] * rden;
      float wx  = numw[j] * rden;
      float wp  = 1.f / (1.f + __expf(-wx));
      float nmj = mem[j] * (1.f - wp) + upd * wp;
      float fj  = fmaxf(nmj + ar[j], 0.f);
      nmv[j] = nmj; fkv[j] = fj;
      n2acc[j] += fj;
    }
    *(float4*)&nm_lds[wave][ml][l8*8]    = make_float4(nmv[0],nmv[1],nmv[2],nmv[3]);
    *(float4*)&nm_lds[wave][ml][l8*8+4]  = make_float4(nmv[4],nmv[5],nmv[6],nmv[7]);
    *(float4*)&fkm_lds[wave][ml][l8*8]   = make_float4(fkv[0],fkv[1],fkv[2],fkv[3]);
    *(float4*)&fkm_lds[wave][ml][l8*8+4] = make_float4(fkv[4],fkv[5],fkv[6],fkv[7]);

    // within-wave LDS visibility (rule #18: waitcnt + sched_barrier)
    asm volatile("s_waitcnt lgkmcnt(0)" ::: "memory");
    __builtin_amdgcn_sched_barrier(0);

    // ---- phase D: matrix2[d][e] += fkm[m][d]*nm[m][e], 8x8 block per lane
    #pragma unroll
    for (int mr = 0; mr < 8; ++mr) {
      float4 ka = *(const float4*)&fkm_lds[wave][mr][ml*8];
      float4 kb = *(const float4*)&fkm_lds[wave][mr][ml*8+4];
      float4 na = *(const float4*)&nm_lds[wave][mr][l8*8];
      float4 nb = *(const float4*)&nm_lds[wave][mr][l8*8+4];
      float kf[8] = {ka.x,ka.y,ka.z,ka.w,kb.x,kb.y,kb.z,kb.w};
      float nf[8] = {na.x,na.y,na.z,na.w,nb.x,nb.y,nb.z,nb.w};
      #pragma unroll
      for (int a = 0; a < 8; ++a)
        #pragma unroll
        for (int e = 0; e < 8; ++e)
          acc[a*8+e] = fmaf(kf[a], nf[e], acc[a*8+e]);
    }
    // drain reads before next iteration's writes reuse the buffers
    asm volatile("s_waitcnt lgkmcnt(0)" ::: "memory");
    __builtin_amdgcn_sched_barrier(0);
  }

  // ================= epilogue =================
  // norm2: reduce across the 8 m-row groups within each wave
  #pragma unroll
  for (int j = 0; j < 8; ++j) {
    float s = n2acc[j];
    s += __shfl_xor(s, 8);
    s += __shfl_xor(s, 16);
    s += __shfl_xor(s, 32);
    n2acc[j] = s;
  }
  if (ml == 0) {
    #pragma unroll
    for (int j = 0; j < 8; ++j) n2stage[wave][l8*8+j] = n2acc[j];
  }
  __syncthreads();
  if (tid < 64) {
    norm2_lds[tid] = (n2stage[0][tid] + n2stage[1][tid]) + (n2stage[2][tid] + n2stage[3][tid]);
  }
  __syncthreads();
  if (tid < 8) {
    float s = 0.f;
    for (int d = 0; d < 64; ++d) s = fmaf(fqb[tid*64+d], norm2_lds[d], s);
    den2_lds[tid] = s + EPSF;
  }

  // matrix2 cross-wave reduce in 16-row chunks fused with num2 = fq @ matrix2
  const int hh = tid >> 5;          // 0..7 (head)
  const int ee = (tid & 31) * 2;    // 0..62 (e pair)
  float num2a = 0.f, num2b = 0.f;
  for (int c = 0; c < 4; ++c) {
    if ((ml >> 1) == c) {
      const int rbase = (ml & 1) * 8;
      #pragma unroll
      for (int a = 0; a < 8; ++a) {
        *(float4*)&stage[wave][rbase + a][l8*8]   = make_float4(acc[a*8+0],acc[a*8+1],acc[a*8+2],acc[a*8+3]);
        *(float4*)&stage[wave][rbase + a][l8*8+4] = make_float4(acc[a*8+4],acc[a*8+5],acc[a*8+6],acc[a*8+7]);
      }
    }
    __syncthreads();
    for (int dl = 0; dl < 16; ++dl) {
      float2 s0 = *(const float2*)&stage[0][dl][ee];
      float2 s1 = *(const float2*)&stage[1][dl][ee];
      float2 s2 = *(const float2*)&stage[2][dl][ee];
      float2 s3 = *(const float2*)&stage[3][dl][ee];
      float v0 = (s0.x + s1.x) + (s2.x + s3.x);
      float v1 = (s0.y + s1.y) + (s2.y + s3.y);
      float fv = fqb[hh*64 + c*16 + dl];
      num2a = fmaf(fv, v0, num2a);
      num2b = fmaf(fv, v1, num2b);
    }
    __syncthreads();
  }
  float rd2 = 1.f / den2_lds[hh];
  attn[(size_t)b*512 + hh*64 + ee]     = num2a * rd2;
  attn[(size_t)b*512 + hh*64 + ee + 1] = num2b * rd2;
}

// =====================================================================
// Kernel 3: out = attn(512x512) @ Wm(512x1024) + bm
// =====================================================================
__global__ __launch_bounds__(256) void out_gemm_kernel(
    const float* __restrict__ A, const float* __restrict__ Wm,
    const float* __restrict__ bm, float* __restrict__ out)
{
  __shared__ float As[16][68];
  __shared__ float Bs[16][68];
  const int col0 = blockIdx.x * 64;
  const int row0 = blockIdx.y * 64;
  const int tid = threadIdx.x;
  const int tr = tid >> 4, tc = tid & 15;
  float acc[4][4] = {};
  for (int k0 = 0; k0 < 512; k0 += 16) {
    {
      int r = tid >> 2, kk = (tid & 3) << 2;
      float4 a4 = *(const float4*)&A[(size_t)(row0 + r) * 512 + k0 + kk];
      As[kk+0][r] = a4.x; As[kk+1][r] = a4.y; As[kk+2][r] = a4.z; As[kk+3][r] = a4.w;
    }
    {
      int kr = tid >> 4, cc = (tid & 15) << 2;
      *(float4*)&Bs[kr][cc] = *(const float4*)&Wm[(size_t)(k0 + kr) * 1024 + col0 + cc];
    }
    __syncthreads();
    #pragma unroll
    for (int k = 0; k < 16; ++k) {
      float4 av4 = *(const float4*)&As[k][tr*4];
      float4 bv4 = *(const float4*)&Bs[k][tc*4];
      float av[4] = {av4.x, av4.y, av4.z, av4.w};
      float bb[4] = {bv4.x, bv4.y, bv4.z, bv4.w};
      #pragma unroll
      for (int i = 0; i < 4; ++i)
        #pragma unroll
        for (int j = 0; j < 4; ++j)
          acc[i][j] = fmaf(av[i], bb[j], acc[i][j]);
    }
    __syncthreads();
  }
  #pragma unroll
  for (int i = 0; i < 4; ++i) {
    int r = row0 + tr*4 + i;
    #pragma unroll
    for (int j = 0; j < 4; ++j) {
      int c = col0 + tc*4 + j;
      out[(size_t)r * 1024 + c] = acc[i][j] + bm[c];
    }
  }
}

extern "C" void kernel_launch(void* const* d_in, const int* in_sizes, int n_in,
                              void* d_out, int out_size, void* d_ws, size_t ws_size,
                              hipStream_t stream)
{
  const float* x    = (const float*)d_in[0];
  const float* mem  = (const float*)d_in[1];
  const float* addr = (const float*)d_in[2];
  const float* Wk   = (const float*)d_in[3];
  const float* bk   = (const float*)d_in[4];
  const float* Wv   = (const float*)d_in[5];
  const float* bv   = (const float*)d_in[6];
  const float* Wq   = (const float*)d_in[7];
  const float* bq   = (const float*)d_in[8];
  const float* Wm   = (const float*)d_in[9];
  const float* bm   = (const float*)d_in[10];
  float* out  = (float*)d_out;
  float* ws   = (float*)d_ws;
  float* proj = ws;                        // 512*2048 floats (4 MB)
  float* attn = ws + (size_t)512 * 2048;   // 512*512 floats (1 MB)

  hipLaunchKernelGGL(proj_gemm_kernel, dim3(32, 8), dim3(256), 0, stream,
                     x, Wk, bk, Wv, bv, Wq, bq, proj);
  hipLaunchKernelGGL(fused_mem_kernel, dim3(512), dim3(256), 0, stream,
                     mem, addr, proj, attn);
  hipLaunchKernelGGL(out_gemm_kernel, dim3(16, 8), dim3(256), 0, stream,
                     attn, Wm, bm, out);
}

// Round 2
// 373.416 us; speedup vs baseline: 1.0184x; 1.0184x over previous
//
#include <hip/hip_runtime.h>
#include <math.h>

#define EPSF 1e-5f

// =====================================================================
// Kernel 1: fused projection GEMM
//   proj[512][2048] = [ relu(x@Wk+bk) (512) | x@Wv+bv (1024) | relu(x@Wq+bq) (512) ]
// =====================================================================
__global__ __launch_bounds__(256) void proj_gemm_kernel(
    const float* __restrict__ x,
    const float* __restrict__ Wk, const float* __restrict__ bk,
    const float* __restrict__ Wv, const float* __restrict__ bv,
    const float* __restrict__ Wq, const float* __restrict__ bq,
    float* __restrict__ proj)
{
  __shared__ float As[16][68];   // [k][m]
  __shared__ float Bs[16][68];   // [k][n]
  const int col0 = blockIdx.x * 64;
  const int row0 = blockIdx.y * 64;
  const float* Bp; const float* bias; int ldb, bcol, relu;
  if (col0 < 512)       { Bp = Wk; bias = bk; ldb = 512;  bcol = col0;        relu = 1; }
  else if (col0 < 1536) { Bp = Wv; bias = bv; ldb = 1024; bcol = col0 - 512;  relu = 0; }
  else                  { Bp = Wq; bias = bq; ldb = 512;  bcol = col0 - 1536; relu = 1; }
  const int tid = threadIdx.x;
  const int tr = tid >> 4, tc = tid & 15;
  float acc[4][4] = {};
  for (int k0 = 0; k0 < 1024; k0 += 16) {
    {
      int r = tid >> 2, kk = (tid & 3) << 2;
      float4 a4 = *(const float4*)&x[(size_t)(row0 + r) * 1024 + k0 + kk];
      As[kk+0][r] = a4.x; As[kk+1][r] = a4.y; As[kk+2][r] = a4.z; As[kk+3][r] = a4.w;
    }
    {
      int kr = tid >> 4, cc = (tid & 15) << 2;
      *(float4*)&Bs[kr][cc] = *(const float4*)&Bp[(size_t)(k0 + kr) * ldb + bcol + cc];
    }
    __syncthreads();
    #pragma unroll
    for (int k = 0; k < 16; ++k) {
      float4 av4 = *(const float4*)&As[k][tr*4];
      float4 bv4 = *(const float4*)&Bs[k][tc*4];
      float av[4] = {av4.x, av4.y, av4.z, av4.w};
      float bb[4] = {bv4.x, bv4.y, bv4.z, bv4.w};
      #pragma unroll
      for (int i = 0; i < 4; ++i)
        #pragma unroll
        for (int j = 0; j < 4; ++j)
          acc[i][j] = fmaf(av[i], bb[j], acc[i][j]);
    }
    __syncthreads();
  }
  #pragma unroll
  for (int i = 0; i < 4; ++i) {
    int r = row0 + tr*4 + i;
    #pragma unroll
    for (int j = 0; j < 4; ++j) {
      int cl = tc*4 + j;
      float v = acc[i][j] + bias[bcol + cl];
      if (relu) v = fmaxf(v, 0.f);
      proj[(size_t)r * 2048 + col0 + cl] = v;
    }
  }
}

// =====================================================================
// Kernel 2: fused memory kernel. One workgroup per batch (512 wgs).
//   R1 changes vs R0:
//   - software prefetch of next-iter addresses/memories rows into
//     registers at loop top (issue-to-use ~1 full iteration)
//   - double-buffered nm/fkm LDS tiles (kills WAR stall across iters)
//   - removed s_waitcnt lgkmcnt(0) drains: same-wave DS ops complete
//     in order; compiler inserts precise lgkmcnt before VALU use.
//     A zero-cost compiler memory barrier keeps IR order.
// =====================================================================
__global__ __launch_bounds__(256, 2) void fused_mem_kernel(
    const float* __restrict__ memories,   // [512][2048][64]
    const float* __restrict__ addresses,  // [2048][64]
    const float* __restrict__ proj,       // [512][2048] = fk|v|fq
    float* __restrict__ attn)             // [512][512]
{
  __shared__ float pbuf[2048];            // fk[8][64] | v[8][128] | fq[8][64]
  __shared__ float nm_lds[2][4][8][76];
  __shared__ float fkm_lds[2][4][8][76];
  __shared__ float n2stage[4][64];
  __shared__ float norm2_lds[64];
  __shared__ float den2_lds[8];
  __shared__ float stage[4][16][64];

  const int b    = blockIdx.x;
  const int tid  = threadIdx.x;
  const int wave = tid >> 6;
  const int lane = tid & 63;
  const int ml   = lane >> 3;   // 0..7 : m-row within tile; also d-block in phase D
  const int l8   = lane & 7;    // 0..7 : d/e slice;        also e-block in phase D

  // stage fk|v|fq (2048 floats) into LDS
  {
    const float* prow = proj + (size_t)b * 2048;
    float4 p0 = *(const float4*)&prow[tid * 8];
    float4 p1 = *(const float4*)&prow[tid * 8 + 4];
    *(float4*)&pbuf[tid * 8]     = p0;
    *(float4*)&pbuf[tid * 8 + 4] = p1;
  }
  const float* fkb = pbuf;
  const float* vb  = pbuf + 512;
  const float* fqb = pbuf + 1536;

  float acc[64];
  #pragma unroll
  for (int i = 0; i < 64; ++i) acc[i] = 0.f;
  float n2acc[8];
  #pragma unroll
  for (int j = 0; j < 8; ++j) n2acc[j] = 0.f;

  const int mbase = wave * 512;
  const float* abase = addresses + (size_t)(mbase + ml) * 64 + l8 * 8;
  const float* mbase_p = memories + ((size_t)b * 2048 + mbase + ml) * 64 + l8 * 8;

  // prologue: load t=0 rows
  float4 aC0 = *(const float4*)abase;
  float4 aC1 = *(const float4*)(abase + 4);
  float4 mC0 = *(const float4*)mbase_p;
  float4 mC1 = *(const float4*)(mbase_p + 4);

  __syncthreads();

  #pragma unroll 1
  for (int t = 0; t < 64; ++t) {
    // ---- prefetch t+1 rows (issued here, consumed next iteration)
    float4 aN0 = aC0, aN1 = aC1, mN0 = mC0, mN1 = mC1;
    if (t < 63) {
      const float* an = abase   + (size_t)(t + 1) * 8 * 64;
      const float* mn = mbase_p + (size_t)(t + 1) * 8 * 64;
      aN0 = *(const float4*)an;
      aN1 = *(const float4*)(an + 4);
      mN0 = *(const float4*)mn;
      mN1 = *(const float4*)(mn + 4);
    }

    float ar[8]  = {aC0.x,aC0.y,aC0.z,aC0.w,aC1.x,aC1.y,aC1.z,aC1.w};
    float mem[8] = {mC0.x,mC0.y,mC0.z,mC0.w,mC1.x,mC1.y,mC1.z,mC1.w};
    float qa[8];
    #pragma unroll
    for (int j = 0; j < 8; ++j) qa[j] = fmaxf(ar[j], 0.f);

    // ---- phase B: partial S[h] over this lane's 8-d slice, then 8-lane-group reduce
    float S[8];
    #pragma unroll
    for (int h = 0; h < 8; ++h) {
      const float* fr = fkb + h * 64 + l8 * 8;
      float4 f0 = *(const float4*)fr;
      float4 f1 = *(const float4*)(fr + 4);
      float s;
      s = qa[0] * f0.x;
      s = fmaf(qa[1], f0.y, s);
      s = fmaf(qa[2], f0.z, s);
      s = fmaf(qa[3], f0.w, s);
      s = fmaf(qa[4], f1.x, s);
      s = fmaf(qa[5], f1.y, s);
      s = fmaf(qa[6], f1.z, s);
      s = fmaf(qa[7], f1.w, s);
      S[h] = s;
    }
    #pragma unroll
    for (int h = 0; h < 8; ++h) {
      float s = S[h];
      s += __shfl_xor(s, 1);
      s += __shfl_xor(s, 2);
      s += __shfl_xor(s, 4);
      S[h] = s;
    }
    float den = ((S[0]+S[1])+(S[2]+S[3])) + ((S[4]+S[5])+(S[6]+S[7])) + EPSF;
    float rden = 1.f / den;

    // ---- phase C: num (e and write halves), elementwise, new_mem/fkm
    float nume[8], numw[8];
    #pragma unroll
    for (int j = 0; j < 8; ++j) { nume[j] = 0.f; numw[j] = 0.f; }
    #pragma unroll
    for (int h = 0; h < 8; ++h) {
      const float* vr = vb + h * 128 + l8 * 8;
      float4 e0 = *(const float4*)vr;
      float4 e1 = *(const float4*)(vr + 4);
      float4 w0 = *(const float4*)(vr + 64);
      float4 w1 = *(const float4*)(vr + 68);
      float sh = S[h];
      nume[0] = fmaf(sh, e0.x, nume[0]);
      nume[1] = fmaf(sh, e0.y, nume[1]);
      nume[2] = fmaf(sh, e0.z, nume[2]);
      nume[3] = fmaf(sh, e0.w, nume[3]);
      nume[4] = fmaf(sh, e1.x, nume[4]);
      nume[5] = fmaf(sh, e1.y, nume[5]);
      nume[6] = fmaf(sh, e1.z, nume[6]);
      nume[7] = fmaf(sh, e1.w, nume[7]);
      numw[0] = fmaf(sh, w0.x, numw[0]);
      numw[1] = fmaf(sh, w0.y, numw[1]);
      numw[2] = fmaf(sh, w0.z, numw[2]);
      numw[3] = fmaf(sh, w0.w, numw[3]);
      numw[4] = fmaf(sh, w1.x, numw[4]);
      numw[5] = fmaf(sh, w1.y, numw[5]);
      numw[6] = fmaf(sh, w1.z, numw[6]);
      numw[7] = fmaf(sh, w1.w, numw[7]);
    }
    const int p = t & 1;
    float nmv[8], fkv[8];
    #pragma unroll
    for (int j = 0; j < 8; ++j) {
      float upd = nume[j] * rden;
      float wx  = numw[j] * rden;
      float wp  = 1.f / (1.f + __expf(-wx));
      float nmj = mem[j] * (1.f - wp) + upd * wp;
      float fj  = fmaxf(nmj + ar[j], 0.f);
      nmv[j] = nmj; fkv[j] = fj;
      n2acc[j] += fj;
    }
    *(float4*)&nm_lds[p][wave][ml][l8*8]    = make_float4(nmv[0],nmv[1],nmv[2],nmv[3]);
    *(float4*)&nm_lds[p][wave][ml][l8*8+4]  = make_float4(nmv[4],nmv[5],nmv[6],nmv[7]);
    *(float4*)&fkm_lds[p][wave][ml][l8*8]   = make_float4(fkv[0],fkv[1],fkv[2],fkv[3]);
    *(float4*)&fkm_lds[p][wave][ml][l8*8+4] = make_float4(fkv[4],fkv[5],fkv[6],fkv[7]);

    // keep IR order write->read; same-wave DS ops complete in order in HW,
    // compiler inserts the precise lgkmcnt before first VALU use.
    asm volatile("" ::: "memory");

    // ---- phase D: matrix2[d][e] += fkm[m][d]*nm[m][e], 8x8 block per lane
    #pragma unroll
    for (int mr = 0; mr < 8; ++mr) {
      float4 ka = *(const float4*)&fkm_lds[p][wave][mr][ml*8];
      float4 kb = *(const float4*)&fkm_lds[p][wave][mr][ml*8+4];
      float4 na = *(const float4*)&nm_lds[p][wave][mr][l8*8];
      float4 nb = *(const float4*)&nm_lds[p][wave][mr][l8*8+4];
      float kf[8] = {ka.x,ka.y,ka.z,ka.w,kb.x,kb.y,kb.z,kb.w};
      float nf[8] = {na.x,na.y,na.z,na.w,nb.x,nb.y,nb.z,nb.w};
      #pragma unroll
      for (int a = 0; a < 8; ++a)
        #pragma unroll
        for (int e = 0; e < 8; ++e)
          acc[a*8+e] = fmaf(kf[a], nf[e], acc[a*8+e]);
    }

    aC0 = aN0; aC1 = aN1; mC0 = mN0; mC1 = mN1;
  }

  // ================= epilogue =================
  #pragma unroll
  for (int j = 0; j < 8; ++j) {
    float s = n2acc[j];
    s += __shfl_xor(s, 8);
    s += __shfl_xor(s, 16);
    s += __shfl_xor(s, 32);
    n2acc[j] = s;
  }
  if (ml == 0) {
    #pragma unroll
    for (int j = 0; j < 8; ++j) n2stage[wave][l8*8+j] = n2acc[j];
  }
  __syncthreads();
  if (tid < 64) {
    norm2_lds[tid] = (n2stage[0][tid] + n2stage[1][tid]) + (n2stage[2][tid] + n2stage[3][tid]);
  }
  __syncthreads();
  if (tid < 8) {
    float s = 0.f;
    for (int d = 0; d < 64; ++d) s = fmaf(fqb[tid*64+d], norm2_lds[d], s);
    den2_lds[tid] = s + EPSF;
  }

  // matrix2 cross-wave reduce in 16-row chunks fused with num2 = fq @ matrix2
  const int hh = tid >> 5;          // 0..7 (head)
  const int ee = (tid & 31) * 2;    // 0..62 (e pair)
  float num2a = 0.f, num2b = 0.f;
  for (int c = 0; c < 4; ++c) {
    if ((ml >> 1) == c) {
      const int rbase = (ml & 1) * 8;
      #pragma unroll
      for (int a = 0; a < 8; ++a) {
        *(float4*)&stage[wave][rbase + a][l8*8]   = make_float4(acc[a*8+0],acc[a*8+1],acc[a*8+2],acc[a*8+3]);
        *(float4*)&stage[wave][rbase + a][l8*8+4] = make_float4(acc[a*8+4],acc[a*8+5],acc[a*8+6],acc[a*8+7]);
      }
    }
    __syncthreads();
    for (int dl = 0; dl < 16; ++dl) {
      float2 s0 = *(const float2*)&stage[0][dl][ee];
      float2 s1 = *(const float2*)&stage[1][dl][ee];
      float2 s2 = *(const float2*)&stage[2][dl][ee];
      float2 s3 = *(const float2*)&stage[3][dl][ee];
      float v0 = (s0.x + s1.x) + (s2.x + s3.x);
      float v1 = (s0.y + s1.y) + (s2.y + s3.y);
      float fv = fqb[hh*64 + c*16 + dl];
      num2a = fmaf(fv, v0, num2a);
      num2b = fmaf(fv, v1, num2b);
    }
    __syncthreads();
  }
  float rd2 = 1.f / den2_lds[hh];
  attn[(size_t)b*512 + hh*64 + ee]     = num2a * rd2;
  attn[(size_t)b*512 + hh*64 + ee + 1] = num2b * rd2;
}

// =====================================================================
// Kernel 3: out = attn(512x512) @ Wm(512x1024) + bm
// =====================================================================
__global__ __launch_bounds__(256) void out_gemm_kernel(
    const float* __restrict__ A, const float* __restrict__ Wm,
    const float* __restrict__ bm, float* __restrict__ out)
{
  __shared__ float As[16][68];
  __shared__ float Bs[16][68];
  const int col0 = blockIdx.x * 64;
  const int row0 = blockIdx.y * 64;
  const int tid = threadIdx.x;
  const int tr = tid >> 4, tc = tid & 15;
  float acc[4][4] = {};
  for (int k0 = 0; k0 < 512; k0 += 16) {
    {
      int r = tid >> 2, kk = (tid & 3) << 2;
      float4 a4 = *(const float4*)&A[(size_t)(row0 + r) * 512 + k0 + kk];
      As[kk+0][r] = a4.x; As[kk+1][r] = a4.y; As[kk+2][r] = a4.z; As[kk+3][r] = a4.w;
    }
    {
      int kr = tid >> 4, cc = (tid & 15) << 2;
      *(float4*)&Bs[kr][cc] = *(const float4*)&Wm[(size_t)(k0 + kr) * 1024 + col0 + cc];
    }
    __syncthreads();
    #pragma unroll
    for (int k = 0; k < 16; ++k) {
      float4 av4 = *(const float4*)&As[k][tr*4];
      float4 bv4 = *(const float4*)&Bs[k][tc*4];
      float av[4] = {av4.x, av4.y, av4.z, av4.w};
      float bb[4] = {bv4.x, bv4.y, bv4.z, bv4.w};
      #pragma unroll
      for (int i = 0; i < 4; ++i)
        #pragma unroll
        for (int j = 0; j < 4; ++j)
          acc[i][j] = fmaf(av[i], bb[j], acc[i][j]);
    }
    __syncthreads();
  }
  #pragma unroll
  for (int i = 0; i < 4; ++i) {
    int r = row0 + tr*4 + i;
    #pragma unroll
    for (int j = 0; j < 4; ++j) {
      int c = col0 + tc*4 + j;
      out[(size_t)r * 1024 + c] = acc[i][j] + bm[c];
    }
  }
}

extern "C" void kernel_launch(void* const* d_in, const int* in_sizes, int n_in,
                              void* d_out, int out_size, void* d_ws, size_t ws_size,
                              hipStream_t stream)
{
  const float* x    = (const float*)d_in[0];
  const float* mem  = (const float*)d_in[1];
  const float* addr = (const float*)d_in[2];
  const float* Wk   = (const float*)d_in[3];
  const float* bk   = (const float*)d_in[4];
  const float* Wv   = (const float*)d_in[5];
  const float* bv   = (const float*)d_in[6];
  const float* Wq   = (const float*)d_in[7];
  const float* bq   = (const float*)d_in[8];
  const float* Wm   = (const float*)d_in[9];
  const float* bm   = (const float*)d_in[10];
  float* out  = (float*)d_out;
  float* ws   = (float*)d_ws;
  float* proj = ws;                        // 512*2048 floats (4 MB)
  float* attn = ws + (size_t)512 * 2048;   // 512*512 floats (1 MB)

  hipLaunchKernelGGL(proj_gemm_kernel, dim3(32, 8), dim3(256), 0, stream,
                     x, Wk, bk, Wv, bv, Wq, bq, proj);
  hipLaunchKernelGGL(fused_mem_kernel, dim3(512), dim3(256), 0, stream,
                     mem, addr, proj, attn);
  hipLaunchKernelGGL(out_gemm_kernel, dim3(16, 8), dim3(256), 0, stream,
                     attn, Wm, bm, out);
}

// Round 3
// 248.903 us; speedup vs baseline: 1.5279x; 1.5002x over previous
//
#include <hip/hip_runtime.h>
#include <math.h>

#define EPSF 1e-5f

typedef __attribute__((ext_vector_type(8))) short bf16x8;
typedef __attribute__((ext_vector_type(16))) float f32x16;

// pack float -> u32 { low16 = hi-bf16 (truncated), high16 = lo-bf16 (residual) }
__device__ __forceinline__ uint32_t packsplit(float x) {
  uint32_t xb = __builtin_bit_cast(uint32_t, x);
  float hi = __builtin_bit_cast(float, xb & 0xFFFF0000u);
  float resid = x - hi;
  return __builtin_amdgcn_perm(__builtin_bit_cast(uint32_t, resid), xb, 0x07060302u);
}

// build an 8xbf16 fragment from 8 packed u32s. sel=0x05040100 -> hi halves,
// sel=0x07060302 -> lo halves. (perm(a,b,s): s byte 0-3 -> b bytes, 4-7 -> a bytes)
__device__ __forceinline__ bf16x8 mkfrag(uint32_t a0, uint32_t a1, uint32_t a2, uint32_t a3,
                                         uint32_t a4, uint32_t a5, uint32_t a6, uint32_t a7,
                                         uint32_t sel) {
  uint4 u;
  u.x = __builtin_amdgcn_perm(a1, a0, sel);
  u.y = __builtin_amdgcn_perm(a3, a2, sel);
  u.z = __builtin_amdgcn_perm(a5, a4, sel);
  u.w = __builtin_amdgcn_perm(a7, a6, sel);
  return __builtin_bit_cast(bf16x8, u);
}

__device__ __forceinline__ float red_xor1(float s) {  // DPP quad_perm [1,0,3,2]
  int t = __builtin_amdgcn_update_dpp(0, __builtin_bit_cast(int, s), 0xB1, 0xF, 0xF, true);
  return s + __builtin_bit_cast(float, t);
}
__device__ __forceinline__ float red_xor2(float s) {  // DPP quad_perm [2,3,0,1]
  int t = __builtin_amdgcn_update_dpp(0, __builtin_bit_cast(int, s), 0x4E, 0xF, 0xF, true);
  return s + __builtin_bit_cast(float, t);
}
__device__ __forceinline__ float red_xor4(float s) {  // ds_swizzle xor 4
  int t = __builtin_amdgcn_ds_swizzle(__builtin_bit_cast(int, s), 0x101F);
  return s + __builtin_bit_cast(float, t);
}

// =====================================================================
// Kernel 1: fused projection GEMM (unchanged)
// =====================================================================
__global__ __launch_bounds__(256) void proj_gemm_kernel(
    const float* __restrict__ x,
    const float* __restrict__ Wk, const float* __restrict__ bk,
    const float* __restrict__ Wv, const float* __restrict__ bv,
    const float* __restrict__ Wq, const float* __restrict__ bq,
    float* __restrict__ proj)
{
  __shared__ float As[16][68];
  __shared__ float Bs[16][68];
  const int col0 = blockIdx.x * 64;
  const int row0 = blockIdx.y * 64;
  const float* Bp; const float* bias; int ldb, bcol, relu;
  if (col0 < 512)       { Bp = Wk; bias = bk; ldb = 512;  bcol = col0;        relu = 1; }
  else if (col0 < 1536) { Bp = Wv; bias = bv; ldb = 1024; bcol = col0 - 512;  relu = 0; }
  else                  { Bp = Wq; bias = bq; ldb = 512;  bcol = col0 - 1536; relu = 1; }
  const int tid = threadIdx.x;
  const int tr = tid >> 4, tc = tid & 15;
  float acc[4][4] = {};
  for (int k0 = 0; k0 < 1024; k0 += 16) {
    {
      int r = tid >> 2, kk = (tid & 3) << 2;
      float4 a4 = *(const float4*)&x[(size_t)(row0 + r) * 1024 + k0 + kk];
      As[kk+0][r] = a4.x; As[kk+1][r] = a4.y; As[kk+2][r] = a4.z; As[kk+3][r] = a4.w;
    }
    {
      int kr = tid >> 4, cc = (tid & 15) << 2;
      *(float4*)&Bs[kr][cc] = *(const float4*)&Bp[(size_t)(k0 + kr) * ldb + bcol + cc];
    }
    __syncthreads();
    #pragma unroll
    for (int k = 0; k < 16; ++k) {
      float4 av4 = *(const float4*)&As[k][tr*4];
      float4 bv4 = *(const float4*)&Bs[k][tc*4];
      float av[4] = {av4.x, av4.y, av4.z, av4.w};
      float bb[4] = {bv4.x, bv4.y, bv4.z, bv4.w};
      #pragma unroll
      for (int i = 0; i < 4; ++i)
        #pragma unroll
        for (int j = 0; j < 4; ++j)
          acc[i][j] = fmaf(av[i], bb[j], acc[i][j]);
    }
    __syncthreads();
  }
  #pragma unroll
  for (int i = 0; i < 4; ++i) {
    int r = row0 + tr*4 + i;
    #pragma unroll
    for (int j = 0; j < 4; ++j) {
      int cl = tc*4 + j;
      float v = acc[i][j] + bias[bcol + cl];
      if (relu) v = fmaxf(v, 0.f);
      proj[(size_t)r * 2048 + col0 + cl] = v;
    }
  }
}

// =====================================================================
// Kernel 2: fused memory kernel, R2 rewrite.
//   - superstep = 16 m rows (2 sub-tiles of 8 sharing fk/v LDS reads)
//   - phase D via mfma_f32_32x32x16_bf16, 2-way bf16 split (3 MFMAs/tile)
//   - per-wave packed LDS tiles [16][76] u32, no barriers in main loop
//   - S reduction: DPP xor1/xor2 (VALU) + ds_swizzle xor4
// =====================================================================
__global__ __launch_bounds__(256, 2) void fused_mem_kernel(
    const float* __restrict__ memories,   // [512][2048][64]
    const float* __restrict__ addresses,  // [2048][64]
    const float* __restrict__ proj,       // [512][2048] = fk|v|fq
    float* __restrict__ attn)             // [512][512]
{
  __shared__ float pbuf[2048];            // fk[8][64] | v[8][128] | fq[8][64]
  __shared__ uint32_t pkF[4][16][76];     // packed fkm (hi|lo), per wave
  __shared__ uint32_t pkN[4][16][76];     // packed new_mem
  __shared__ float stage[4][16][66];
  __shared__ float n2stage[4][64];
  __shared__ float norm2_lds[64];
  __shared__ float den2_lds[8];

  const int b    = blockIdx.x;
  const int tid  = threadIdx.x;
  const int wave = tid >> 6;
  const int lane = tid & 63;
  const int ml   = lane >> 3;     // m-row within 8-tile
  const int l8   = lane & 7;      // 8-elem slice of d/e
  const int g32  = lane >> 5;     // MFMA k-group
  const int c32  = lane & 31;     // MFMA row/col

  {
    const float* prow = proj + (size_t)b * 2048;
    *(float4*)&pbuf[tid*8]   = *(const float4*)&prow[tid*8];
    *(float4*)&pbuf[tid*8+4] = *(const float4*)&prow[tid*8+4];
  }
  const float* fkb = pbuf;
  const float* vb  = pbuf + 512;
  const float* fqb = pbuf + 1536;

  f32x16 acc00, acc01, acc10, acc11;
  #pragma unroll
  for (int r = 0; r < 16; ++r) { acc00[r] = 0.f; acc01[r] = 0.f; acc10[r] = 0.f; acc11[r] = 0.f; }
  float n2acc[8];
  #pragma unroll
  for (int j = 0; j < 8; ++j) n2acc[j] = 0.f;

  uint32_t (*pF)[76] = pkF[wave];
  uint32_t (*pN)[76] = pkN[wave];

  const int mbase = wave * 512;
  const float* aB = addresses + (size_t)mbase * 64;
  const float* mB = memories + ((size_t)b * 2048 + mbase) * 64;

  __syncthreads();

  // MFMA over the 16 rows currently in pk buffers (A=fkm^T, B=nm; 2x2 tiles x {hh,hl,lh})
  auto do_mfma = [&]() {
    uint32_t rf0[8], rf1[8], rn0[8], rn1[8];
    #pragma unroll
    for (int e = 0; e < 8; ++e) {
      const int row = g32*8 + e;
      rf0[e] = pF[row][c32];
      rf1[e] = pF[row][32 + c32];
      rn0[e] = pN[row][c32];
      rn1[e] = pN[row][32 + c32];
    }
    bf16x8 A0h = mkfrag(rf0[0],rf0[1],rf0[2],rf0[3],rf0[4],rf0[5],rf0[6],rf0[7], 0x05040100u);
    bf16x8 A0l = mkfrag(rf0[0],rf0[1],rf0[2],rf0[3],rf0[4],rf0[5],rf0[6],rf0[7], 0x07060302u);
    bf16x8 A1h = mkfrag(rf1[0],rf1[1],rf1[2],rf1[3],rf1[4],rf1[5],rf1[6],rf1[7], 0x05040100u);
    bf16x8 A1l = mkfrag(rf1[0],rf1[1],rf1[2],rf1[3],rf1[4],rf1[5],rf1[6],rf1[7], 0x07060302u);
    bf16x8 B0h = mkfrag(rn0[0],rn0[1],rn0[2],rn0[3],rn0[4],rn0[5],rn0[6],rn0[7], 0x05040100u);
    bf16x8 B0l = mkfrag(rn0[0],rn0[1],rn0[2],rn0[3],rn0[4],rn0[5],rn0[6],rn0[7], 0x07060302u);
    bf16x8 B1h = mkfrag(rn1[0],rn1[1],rn1[2],rn1[3],rn1[4],rn1[5],rn1[6],rn1[7], 0x05040100u);
    bf16x8 B1l = mkfrag(rn1[0],rn1[1],rn1[2],rn1[3],rn1[4],rn1[5],rn1[6],rn1[7], 0x07060302u);
    acc00 = __builtin_amdgcn_mfma_f32_32x32x16_bf16(A0h, B0h, acc00, 0, 0, 0);
    acc00 = __builtin_amdgcn_mfma_f32_32x32x16_bf16(A0h, B0l, acc00, 0, 0, 0);
    acc00 = __builtin_amdgcn_mfma_f32_32x32x16_bf16(A0l, B0h, acc00, 0, 0, 0);
    acc01 = __builtin_amdgcn_mfma_f32_32x32x16_bf16(A0h, B1h, acc01, 0, 0, 0);
    acc01 = __builtin_amdgcn_mfma_f32_32x32x16_bf16(A0h, B1l, acc01, 0, 0, 0);
    acc01 = __builtin_amdgcn_mfma_f32_32x32x16_bf16(A0l, B1h, acc01, 0, 0, 0);
    acc10 = __builtin_amdgcn_mfma_f32_32x32x16_bf16(A1h, B0h, acc10, 0, 0, 0);
    acc10 = __builtin_amdgcn_mfma_f32_32x32x16_bf16(A1h, B0l, acc10, 0, 0, 0);
    acc10 = __builtin_amdgcn_mfma_f32_32x32x16_bf16(A1l, B0h, acc10, 0, 0, 0);
    acc11 = __builtin_amdgcn_mfma_f32_32x32x16_bf16(A1h, B1h, acc11, 0, 0, 0);
    acc11 = __builtin_amdgcn_mfma_f32_32x32x16_bf16(A1h, B1l, acc11, 0, 0, 0);
    acc11 = __builtin_amdgcn_mfma_f32_32x32x16_bf16(A1l, B1h, acc11, 0, 0, 0);
  };

#define ELEMPACK(ARX, MEMX, NEX, NWX, RDENX, PAR) do {                         \
    uint32_t pf_[8], pn_[8];                                                   \
    _Pragma("unroll")                                                          \
    for (int j = 0; j < 8; ++j) {                                              \
      float upd = NEX[j] * (RDENX);                                            \
      float wx  = NWX[j] * (RDENX);                                            \
      float wp  = 1.f / (1.f + __expf(-wx));                                   \
      float nmj = MEMX[j] * (1.f - wp) + upd * wp;                             \
      float fj  = fmaxf(nmj + ARX[j], 0.f);                                    \
      n2acc[j] += fj;                                                          \
      pn_[j] = packsplit(nmj);                                                 \
      pf_[j] = packsplit(fj);                                                  \
    }                                                                          \
    uint32_t* rf_ = &pF[(PAR)*8 + ml][l8*8];                                   \
    *(uint4*)rf_     = make_uint4(pf_[0], pf_[1], pf_[2], pf_[3]);             \
    *(uint4*)(rf_+4) = make_uint4(pf_[4], pf_[5], pf_[6], pf_[7]);             \
    uint32_t* rn_ = &pN[(PAR)*8 + ml][l8*8];                                   \
    *(uint4*)rn_     = make_uint4(pn_[0], pn_[1], pn_[2], pn_[3]);             \
    *(uint4*)(rn_+4) = make_uint4(pn_[4], pn_[5], pn_[6], pn_[7]);             \
  } while (0)

  #pragma unroll 1
  for (int s = 0; s < 32; ++s) {
    asm volatile("" ::: "memory");  // block LICM of s-invariant fk/v LDS reads

    // ---- global loads for this superstep (2 sub-tiles x 8 rows)
    const float* a0p = aB + ((size_t)s*16 + ml)*64 + l8*8;
    float4 A00 = *(const float4*)a0p;
    float4 A01 = *(const float4*)(a0p + 4);
    float4 A10 = *(const float4*)(a0p + 512);
    float4 A11 = *(const float4*)(a0p + 516);
    const float* m0p = mB + ((size_t)s*16 + ml)*64 + l8*8;
    float4 M00 = *(const float4*)m0p;
    float4 M01 = *(const float4*)(m0p + 4);
    float4 M10 = *(const float4*)(m0p + 512);
    float4 M11 = *(const float4*)(m0p + 516);

    // ---- MFMA for previous superstep's pk data (covers VMEM latency)
    if (s) do_mfma();

    float ar0[8] = {A00.x,A00.y,A00.z,A00.w,A01.x,A01.y,A01.z,A01.w};
    float ar1[8] = {A10.x,A10.y,A10.z,A10.w,A11.x,A11.y,A11.z,A11.w};
    float mem0[8] = {M00.x,M00.y,M00.z,M00.w,M01.x,M01.y,M01.z,M01.w};
    float mem1[8] = {M10.x,M10.y,M10.z,M10.w,M11.x,M11.y,M11.z,M11.w};
    float qa0[8], qa1[8];
    #pragma unroll
    for (int j = 0; j < 8; ++j) { qa0[j] = fmaxf(ar0[j], 0.f); qa1[j] = fmaxf(ar1[j], 0.f); }

    // ---- phase B: S = qa @ fk^T for both sub-tiles (shared fk reads)
    float S0[8], S1[8];
    #pragma unroll
    for (int h = 0; h < 8; ++h) {
      const float* fr = fkb + h*64 + l8*8;
      float4 f0 = *(const float4*)fr;
      float4 f1 = *(const float4*)(fr + 4);
      float s0 = qa0[0]*f0.x; float s1 = qa1[0]*f0.x;
      s0 = fmaf(qa0[1], f0.y, s0); s1 = fmaf(qa1[1], f0.y, s1);
      s0 = fmaf(qa0[2], f0.z, s0); s1 = fmaf(qa1[2], f0.z, s1);
      s0 = fmaf(qa0[3], f0.w, s0); s1 = fmaf(qa1[3], f0.w, s1);
      s0 = fmaf(qa0[4], f1.x, s0); s1 = fmaf(qa1[4], f1.x, s1);
      s0 = fmaf(qa0[5], f1.y, s0); s1 = fmaf(qa1[5], f1.y, s1);
      s0 = fmaf(qa0[6], f1.z, s0); s1 = fmaf(qa1[6], f1.z, s1);
      s0 = fmaf(qa0[7], f1.w, s0); s1 = fmaf(qa1[7], f1.w, s1);
      S0[h] = s0; S1[h] = s1;
    }
    #pragma unroll
    for (int h = 0; h < 8; ++h) {
      S0[h] = red_xor4(red_xor2(red_xor1(S0[h])));
      S1[h] = red_xor4(red_xor2(red_xor1(S1[h])));
    }
    float den0 = ((S0[0]+S0[1])+(S0[2]+S0[3])) + ((S0[4]+S0[5])+(S0[6]+S0[7])) + EPSF;
    float den1 = ((S1[0]+S1[1])+(S1[2]+S1[3])) + ((S1[4]+S1[5])+(S1[6]+S1[7])) + EPSF;
    float rden0 = 1.f / den0;
    float rden1 = 1.f / den1;

    // ---- phase C: num halves for both sub-tiles (shared v reads)
    float ne0[8], nw0[8], ne1[8], nw1[8];
    #pragma unroll
    for (int j = 0; j < 8; ++j) { ne0[j]=0.f; nw0[j]=0.f; ne1[j]=0.f; nw1[j]=0.f; }
    #pragma unroll
    for (int h = 0; h < 8; ++h) {
      const float* vr = vb + h*128 + l8*8;
      float4 e0 = *(const float4*)vr;
      float4 e1 = *(const float4*)(vr + 4);
      float4 w0 = *(const float4*)(vr + 64);
      float4 w1 = *(const float4*)(vr + 68);
      float sh0 = S0[h], sh1 = S1[h];
      ne0[0] = fmaf(sh0, e0.x, ne0[0]); ne1[0] = fmaf(sh1, e0.x, ne1[0]);
      ne0[1] = fmaf(sh0, e0.y, ne0[1]); ne1[1] = fmaf(sh1, e0.y, ne1[1]);
      ne0[2] = fmaf(sh0, e0.z, ne0[2]); ne1[2] = fmaf(sh1, e0.z, ne1[2]);
      ne0[3] = fmaf(sh0, e0.w, ne0[3]); ne1[3] = fmaf(sh1, e0.w, ne1[3]);
      ne0[4] = fmaf(sh0, e1.x, ne0[4]); ne1[4] = fmaf(sh1, e1.x, ne1[4]);
      ne0[5] = fmaf(sh0, e1.y, ne0[5]); ne1[5] = fmaf(sh1, e1.y, ne1[5]);
      ne0[6] = fmaf(sh0, e1.z, ne0[6]); ne1[6] = fmaf(sh1, e1.z, ne1[6]);
      ne0[7] = fmaf(sh0, e1.w, ne0[7]); ne1[7] = fmaf(sh1, e1.w, ne1[7]);
      nw0[0] = fmaf(sh0, w0.x, nw0[0]); nw1[0] = fmaf(sh1, w0.x, nw1[0]);
      nw0[1] = fmaf(sh0, w0.y, nw0[1]); nw1[1] = fmaf(sh1, w0.y, nw1[1]);
      nw0[2] = fmaf(sh0, w0.z, nw0[2]); nw1[2] = fmaf(sh1, w0.z, nw1[2]);
      nw0[3] = fmaf(sh0, w0.w, nw0[3]); nw1[3] = fmaf(sh1, w0.w, nw1[3]);
      nw0[4] = fmaf(sh0, w1.x, nw0[4]); nw1[4] = fmaf(sh1, w1.x, nw1[4]);
      nw0[5] = fmaf(sh0, w1.y, nw0[5]); nw1[5] = fmaf(sh1, w1.y, nw1[5]);
      nw0[6] = fmaf(sh0, w1.z, nw0[6]); nw1[6] = fmaf(sh1, w1.z, nw1[6]);
      nw0[7] = fmaf(sh0, w1.w, nw0[7]); nw1[7] = fmaf(sh1, w1.w, nw1[7]);
    }

    // ---- elementwise + pack + per-wave LDS write (rows 0-7 then 8-15)
    ELEMPACK(ar0, mem0, ne0, nw0, rden0, 0);
    ELEMPACK(ar1, mem1, ne1, nw1, rden1, 1);
  }
  do_mfma();  // final superstep

  // ================= epilogue =================
  #pragma unroll
  for (int j = 0; j < 8; ++j) {
    float v = n2acc[j];
    v += __shfl_xor(v, 8);
    v += __shfl_xor(v, 16);
    v += __shfl_xor(v, 32);
    n2acc[j] = v;
  }
  if (ml == 0) {
    #pragma unroll
    for (int j = 0; j < 8; ++j) n2stage[wave][l8*8+j] = n2acc[j];
  }
  __syncthreads();
  if (tid < 64) {
    norm2_lds[tid] = (n2stage[0][tid] + n2stage[1][tid]) + (n2stage[2][tid] + n2stage[3][tid]);
  }
  __syncthreads();
  if (tid < 8) {
    float sum = 0.f;
    for (int d = 0; d < 64; ++d) sum = fmaf(fqb[tid*64+d], norm2_lds[d], sum);
    den2_lds[tid] = sum + EPSF;
  }

  // 4 passes of 16 d-rows: dump per-wave C tiles, reduce + num2
  const int hh = tid >> 5;
  const int ee = (tid & 31) * 2;
  float num2a = 0.f, num2b = 0.f;
  #pragma unroll
  for (int p = 0; p < 4; ++p) {
    const int ti = p >> 1, rh = p & 1;
    #pragma unroll
    for (int q = 0; q < 8; ++q) {
      const int rr = (q & 3) + 8*((q >> 2) & 1) + 4*g32;   // in-pass d row
      const int r  = rh*8 + q;
      float v0, v1;
      if (ti == 0) { v0 = acc00[r]; v1 = acc01[r]; }
      else         { v0 = acc10[r]; v1 = acc11[r]; }
      stage[wave][rr][c32]      = v0;
      stage[wave][rr][32 + c32] = v1;
    }
    __syncthreads();
    #pragma unroll 8
    for (int dl = 0; dl < 16; ++dl) {
      float2 s0 = *(const float2*)&stage[0][dl][ee];
      float2 s1 = *(const float2*)&stage[1][dl][ee];
      float2 s2 = *(const float2*)&stage[2][dl][ee];
      float2 s3 = *(const float2*)&stage[3][dl][ee];
      float v0 = (s0.x + s1.x) + (s2.x + s3.x);
      float v1 = (s0.y + s1.y) + (s2.y + s3.y);
      float fv = fqb[hh*64 + p*16 + dl];
      num2a = fmaf(fv, v0, num2a);
      num2b = fmaf(fv, v1, num2b);
    }
    __syncthreads();
  }
  float rd2 = 1.f / den2_lds[hh];
  attn[(size_t)b*512 + hh*64 + ee]     = num2a * rd2;
  attn[(size_t)b*512 + hh*64 + ee + 1] = num2b * rd2;
#undef ELEMPACK
}

// =====================================================================
// Kernel 3: out = attn(512x512) @ Wm(512x1024) + bm (unchanged)
// =====================================================================
__global__ __launch_bounds__(256) void out_gemm_kernel(
    const float* __restrict__ A, const float* __restrict__ Wm,
    const float* __restrict__ bm, float* __restrict__ out)
{
  __shared__ float As[16][68];
  __shared__ float Bs[16][68];
  const int col0 = blockIdx.x * 64;
  const int row0 = blockIdx.y * 64;
  const int tid = threadIdx.x;
  const int tr = tid >> 4, tc = tid & 15;
  float acc[4][4] = {};
  for (int k0 = 0; k0 < 512; k0 += 16) {
    {
      int r = tid >> 2, kk = (tid & 3) << 2;
      float4 a4 = *(const float4*)&A[(size_t)(row0 + r) * 512 + k0 + kk];
      As[kk+0][r] = a4.x; As[kk+1][r] = a4.y; As[kk+2][r] = a4.z; As[kk+3][r] = a4.w;
    }
    {
      int kr = tid >> 4, cc = (tid & 15) << 2;
      *(float4*)&Bs[kr][cc] = *(const float4*)&Wm[(size_t)(k0 + kr) * 1024 + col0 + cc];
    }
    __syncthreads();
    #pragma unroll
    for (int k = 0; k < 16; ++k) {
      float4 av4 = *(const float4*)&As[k][tr*4];
      float4 bv4 = *(const float4*)&Bs[k][tc*4];
      float av[4] = {av4.x, av4.y, av4.z, av4.w};
      float bb[4] = {bv4.x, bv4.y, bv4.z, bv4.w};
      #pragma unroll
      for (int i = 0; i < 4; ++i)
        #pragma unroll
        for (int j = 0; j < 4; ++j)
          acc[i][j] = fmaf(av[i], bb[j], acc[i][j]);
    }
    __syncthreads();
  }
  #pragma unroll
  for (int i = 0; i < 4; ++i) {
    int r = row0 + tr*4 + i;
    #pragma unroll
    for (int j = 0; j < 4; ++j) {
      int c = col0 + tc*4 + j;
      out[(size_t)r * 1024 + c] = acc[i][j] + bm[c];
    }
  }
}

extern "C" void kernel_launch(void* const* d_in, const int* in_sizes, int n_in,
                              void* d_out, int out_size, void* d_ws, size_t ws_size,
                              hipStream_t stream)
{
  const float* x    = (const float*)d_in[0];
  const float* mem  = (const float*)d_in[1];
  const float* addr = (const float*)d_in[2];
  const float* Wk   = (const float*)d_in[3];
  const float* bk   = (const float*)d_in[4];
  const float* Wv   = (const float*)d_in[5];
  const float* bv   = (const float*)d_in[6];
  const float* Wq   = (const float*)d_in[7];
  const float* bq   = (const float*)d_in[8];
  const float* Wm   = (const float*)d_in[9];
  const float* bm   = (const float*)d_in[10];
  float* out  = (float*)d_out;
  float* ws   = (float*)d_ws;
  float* proj = ws;                        // 512*2048 floats (4 MB)
  float* attn = ws + (size_t)512 * 2048;   // 512*512 floats (1 MB)

  hipLaunchKernelGGL(proj_gemm_kernel, dim3(32, 8), dim3(256), 0, stream,
                     x, Wk, bk, Wv, bv, Wq, bq, proj);
  hipLaunchKernelGGL(fused_mem_kernel, dim3(512), dim3(256), 0, stream,
                     mem, addr, proj, attn);
  hipLaunchKernelGGL(out_gemm_kernel, dim3(16, 8), dim3(256), 0, stream,
                     attn, Wm, bm, out);
}